// Round 10
// baseline (605.908 us; speedup 1.0000x reference)
//
#include <hip/hip_runtime.h>
#include <math.h>

// 2-layer ReLU RNN, B=256, T=1000 (input 800 + zero pad), H=128, F=5.
// R25: REGISTER-RESIDENT recurrence. R20==R23 (885 cyc/step) under three
// issue profiles proved the floor is the per-step LDS round-trip + barrier
// convoy (~550 cyc), not issue. Now each layer's recurrence lives in ONE
// wave's registers:
//  - lane L holds h-pair q=L (h16x2) AND computes output rows 2L,2L+1 ->
//    output IS next step's input distribution (no redistribution).
//  - matvec = 4 rings x 16 ticks x 2 fdot2. Ring x base: own h (x=0),
//    ds_swizzle xor16 (x=1, 0x401F), ds_bpermute xor32/48 (x=2,3) - issued
//    right after h is computed, hidden under ring0's 32 fdot2.
//  - within a ring: XOR-DPP Gray walk with offsets o_r = r exactly:
//    transitions xor{1,3,1,7,1,3,1,15,...} = DPP 0xB1/0x1B/0x141/0x140
//    (all verified encodings, all XOR => direction-unambiguous).
//    Weight at ring x, tick r: col-pair q = 16*(R^x) + (p^r), rows 2L,2L+1.
//  - h published per step via ONE fire-and-forget ds_write (for A/y).
//  - __syncthreads only every 8 steps (after s==7 mod 8). Schedule: SK1=24,
//    A@s=17+16k (u=s-17..s-2), y@s=41+16k (t=s-41+slot), xc@s=9+16k
//    (t=s+7..s+22, prologue t=0..15). All producer->consumer gaps cross a
//    barrier (A worst case: consume >= sA+7 > barrier at sA+6); 32-deep
//    slots disjoint (xc[t] rewritten at burst s+32; A[u] at u+34..; ring1[t]
//    at t+56). NSTEP=1024.
// Waves (384 thr, SIMD=wv&3): wv0=h0 (S0), wv1=h1 (S1), wv2/3=A-MFMA
// (S2/3, R20-verified layouts), wv4=y (S0), wv5=xc (S1).

#define TT    1000
#define TIN   800
#define HD    128
#define NF    5
#define BATCH 256
#define RS    136           // h16 ring row stride (272B)
#define AS    132           // f32 ring row stride (528B)
#define SK1   24            // h1[u] computed at step u+24
#define NSTEP 1024

typedef _Float16 h16x2 __attribute__((ext_vector_type(2)));
typedef _Float16 h16x8 __attribute__((ext_vector_type(8)));
typedef float    f32x4 __attribute__((ext_vector_type(4)));

template<int CTRL>
__device__ __forceinline__ float dpp_mov(float v) {
    union { float f; int i; } u, r;
    u.f = v;
    r.i = __builtin_amdgcn_update_dpp(0, u.i, CTRL, 0xF, 0xF, true);
    return r.f;
}
__device__ __forceinline__ int h2i(h16x2 v) { union { h16x2 h; int i; } u; u.h = v; return u.i; }
__device__ __forceinline__ h16x2 i2h(int v) { union { h16x2 h; int i; } u; u.i = v; return u.h; }
template<int CTRL>
__device__ __forceinline__ h16x2 dpp_h2(h16x2 v) {
    return i2h(__builtin_amdgcn_update_dpp(0, h2i(v), CTRL, 0xF, 0xF, true));
}

// one fdot2 pair: rows 2L (a0) and 2L+1 (a1) against current col-pair
#define TICK(x, r) \
    a0 = __builtin_amdgcn_fdot2(W.wp[x][r][0], cur, a0, false); \
    a1 = __builtin_amdgcn_fdot2(W.wp[x][r][1], cur, a1, false);
// 16-tick ring: cumulative XOR offsets o_r = r (transitions 1,3,1,7,1,3,1,15,...)
#define RING16(x, V) { h16x2 cur = (V); float a0 = 0.f, a1 = 0.f; \
    TICK(x,0)  cur = dpp_h2<0xB1>(cur);  TICK(x,1)  cur = dpp_h2<0x1B>(cur);  \
    TICK(x,2)  cur = dpp_h2<0xB1>(cur);  TICK(x,3)  cur = dpp_h2<0x141>(cur); \
    TICK(x,4)  cur = dpp_h2<0xB1>(cur);  TICK(x,5)  cur = dpp_h2<0x1B>(cur);  \
    TICK(x,6)  cur = dpp_h2<0xB1>(cur);  TICK(x,7)  cur = dpp_h2<0x140>(cur); \
    TICK(x,8)  cur = dpp_h2<0xB1>(cur);  TICK(x,9)  cur = dpp_h2<0x1B>(cur);  \
    TICK(x,10) cur = dpp_h2<0xB1>(cur);  TICK(x,11) cur = dpp_h2<0x141>(cur); \
    TICK(x,12) cur = dpp_h2<0xB1>(cur);  TICK(x,13) cur = dpp_h2<0x1B>(cur);  \
    TICK(x,14) cur = dpp_h2<0xB1>(cur);  TICK(x,15) t0 += a0; t1 += a1; }

__global__ __launch_bounds__(384, 2) void rnn_rr(
    const float* __restrict__ x,        // [256,800,5]
    const float* __restrict__ h_state,  // [2,256,128]
    const float* __restrict__ w_ih0,    // [128,5]
    const float* __restrict__ w_hh0,    // [128,128]
    const float* __restrict__ b_ih0,    // [128]
    const float* __restrict__ b_hh0,    // [128]
    const float* __restrict__ w_ih1,    // [128,128]
    const float* __restrict__ w_hh1,    // [128,128]
    const float* __restrict__ b_ih1,    // [128]
    const float* __restrict__ b_hh1,    // [128]
    const float* __restrict__ w_out,    // [1,128]
    const float* __restrict__ b_out,    // [1]
    float* __restrict__ out)            // [204800 y] ++ [65536 final states]
{
    __shared__ __align__(16) _Float16 x_h[TIN * 8];      // 12.8 KB
    __shared__ __align__(16) _Float16 ring0[32][RS];     // h0 history (pub)
    __shared__ __align__(16) _Float16 ring1[32][RS];     // h1 history (pub)
    __shared__ __align__(16) float    A_f[32][AS];       // Wih1.h0 ring
    __shared__ __align__(16) float    xc_f[32][AS];      // Wih0.x ring
    __shared__ float y_lds[TIN];

    const int tid  = threadIdx.x;
    const int bb   = blockIdx.x;
    const int wv   = tid >> 6;          // 0..5 (SIMD = wv&3)
    const int lane = tid & 63;
    const int R    = lane >> 4;         // 16-lane row
    const int p    = lane & 15;

    // ---- stage x[bb] into LDS (fp16, stride 8, pads zero) ----
    for (int i = tid; i < TIN * 8; i += 384) x_h[i] = (_Float16)0.f;
    __syncthreads();
    for (int i = tid; i < TIN * NF; i += 384) {
        int t = i / 5, f = i - 5 * t;
        x_h[t * 8 + f] = (_Float16)x[bb * (TIN * NF) + i];
    }

    // ---- weight store (union shared across roles) ----
    union WU {
        h16x2 wp[4][16][2]; // engines: ring x, tick r, rows {2L, 2L+1}
        h16x8 af[4][4];     // wv2,3: Wih1 MFMA A-frags
    } W;
    h16x2 wo[16];           // wv4
    h16x2 xwa[3], xwb[3];   // wv5
    float bias0 = 0.f, bias1 = 0.f;
    h16x2 hc = { (_Float16)0.f, (_Float16)0.f };    // engine state pair

    if (wv < 2) {
        const float* Wsrc = (wv == 0) ? w_hh0 : w_hh1;
        #pragma unroll
        for (int xx = 0; xx < 4; ++xx) {
            #pragma unroll
            for (int r = 0; r < 16; ++r) {
                const int q = 16 * (R ^ xx) + (p ^ r);
                const float* c0 = Wsrc + (2 * lane) * HD + 2 * q;
                const float* c1 = Wsrc + (2 * lane + 1) * HD + 2 * q;
                h16x2 w0 = { (_Float16)c0[0], (_Float16)c0[1] };
                h16x2 w1 = { (_Float16)c1[0], (_Float16)c1[1] };
                W.wp[xx][r][0] = w0;
                W.wp[xx][r][1] = w1;
            }
        }
        if (wv == 0) {
            bias0 = b_ih0[2 * lane] + b_hh0[2 * lane];
            bias1 = b_ih0[2 * lane + 1] + b_hh0[2 * lane + 1];
            hc[0] = (_Float16)h_state[bb * HD + 2 * lane];
            hc[1] = (_Float16)h_state[bb * HD + 2 * lane + 1];
        } else {
            bias0 = b_ih1[2 * lane] + b_hh1[2 * lane];
            bias1 = b_ih1[2 * lane + 1] + b_hh1[2 * lane + 1];
            hc[0] = (_Float16)h_state[BATCH * HD + bb * HD + 2 * lane];
            hc[1] = (_Float16)h_state[BATCH * HD + bb * HD + 2 * lane + 1];
        }
    } else if (wv < 4) {
        const int m0 = (wv == 2) ? 0 : 64;
        #pragma unroll
        for (int mt = 0; mt < 4; ++mt) {
            #pragma unroll
            for (int kt = 0; kt < 4; ++kt) {
                const float* rp = w_ih1 + (m0 + mt * 16 + (lane & 15)) * HD
                                + kt * 32 + (lane >> 4) * 8;
                h16x8 v;
                #pragma unroll
                for (int j = 0; j < 8; ++j) v[j] = (_Float16)rp[j];
                W.af[mt][kt] = v;
            }
        }
    } else if (wv == 4) {
        const int c4 = lane & 3;
        #pragma unroll
        for (int t = 0; t < 16; ++t) {
            h16x2 w2 = { (_Float16)w_out[c4 * 32 + 2 * t],
                         (_Float16)w_out[c4 * 32 + 2 * t + 1] };
            wo[t] = w2;
        }
    } else {
        #pragma unroll
        for (int k = 0; k < 3; ++k) {
            _Float16 a0 = (_Float16)w_ih0[(2 * lane) * NF + 2 * k];
            _Float16 a1 = (2 * k + 1 < NF) ? (_Float16)w_ih0[(2 * lane) * NF + 2 * k + 1] : (_Float16)0.f;
            _Float16 b0 = (_Float16)w_ih0[(2 * lane + 1) * NF + 2 * k];
            _Float16 b1 = (2 * k + 1 < NF) ? (_Float16)w_ih0[(2 * lane + 1) * NF + 2 * k + 1] : (_Float16)0.f;
            h16x2 wa = { a0, a1 }; xwa[k] = wa;
            h16x2 wb = { b0, b1 }; xwb[k] = wb;
        }
    }
    const float bout = b_out[0];
    const int a32 = (lane ^ 32) << 2;   // bpermute byte addrs (constant)
    const int a48 = (lane ^ 48) << 2;

    float hfin0 = 0.f, hfin1 = 0.f;

    // xc burst: lane owns rows 2*lane, 2*lane+1; 16 t's per burst.
    auto xc_burst = [&](int tb) {
        #pragma unroll
        for (int ti = 0; ti < 16; ++ti) {
            const int t = tb + ti;
            h16x8 xv = *(const h16x8*)(&x_h[t * 8]);
            h16x2 xp0 = { xv[0], xv[1] };
            h16x2 xp1 = { xv[2], xv[3] };
            h16x2 xp2 = { xv[4], xv[5] };
            float c0 = __builtin_amdgcn_fdot2(xwa[2], xp2, 0.f, false);
            c0 = __builtin_amdgcn_fdot2(xwa[1], xp1, c0, false);
            c0 = __builtin_amdgcn_fdot2(xwa[0], xp0, c0, false);
            float c1 = __builtin_amdgcn_fdot2(xwb[2], xp2, 0.f, false);
            c1 = __builtin_amdgcn_fdot2(xwb[1], xp1, c1, false);
            c1 = __builtin_amdgcn_fdot2(xwb[0], xp0, c1, false);
            *(float2*)(&xc_f[t & 31][2 * lane]) = make_float2(c0, c1);
        }
    };

    __syncthreads();
    if (wv == 5) xc_burst(0);       // prologue: t = 0..15
    __syncthreads();

    // register-ring matvec: shuffles issued first (hidden under ring 0)
    auto matrot = [&](h16x2 hin, float& t0, float& t1) {
        const int hb = h2i(hin);
        h16x2 vB = i2h(__builtin_amdgcn_ds_swizzle(hb, 0x401F));     // xor16
        h16x2 vC = i2h(__builtin_amdgcn_ds_bpermute(a32, hb));       // xor32
        h16x2 vD = i2h(__builtin_amdgcn_ds_bpermute(a48, hb));       // xor48
        t0 = 0.f; t1 = 0.f;
        RING16(0, hin)
        RING16(1, vB)
        RING16(2, vC)
        RING16(3, vD)
    };

    for (int s = 0; s < NSTEP; ++s) {
        if (wv == 0) {
            // h0[s] = relu(Whh0.h0[s-1] + xc[s] + b) - all in registers
            if (s < TT) {
                float2 xcv = make_float2(0.f, 0.f);
                if (s < TIN) xcv = *(const float2*)(&xc_f[s & 31][2 * lane]);
                float t0, t1;
                matrot(hc, t0, t1);
                float v0 = fmaxf(t0 + bias0 + xcv.x, 0.f);
                float v1 = fmaxf(t1 + bias1 + xcv.y, 0.f);
                h16x2 nh = { (_Float16)v0, (_Float16)v1 };
                hc = nh;
                *(h16x2*)(&ring0[s & 31][2 * lane]) = nh;   // publish
                if (s == TT - 1) { hfin0 = v0; hfin1 = v1; }
            }
        } else if (wv == 1) {
            // h1[u] = relu(Whh1.h1[u-1] + A[u] + b), u = s - 24
            if (s >= SK1) {
                const int u = s - SK1;
                float2 av = *(const float2*)(&A_f[u & 31][2 * lane]);
                float t0, t1;
                matrot(hc, t0, t1);
                float v0 = fmaxf(t0 + bias0 + av.x, 0.f);
                float v1 = fmaxf(t1 + bias1 + av.y, 0.f);
                h16x2 nh = { (_Float16)v0, (_Float16)v1 };
                hc = nh;
                *(h16x2*)(&ring1[u & 31][2 * lane]) = nh;   // publish
                if (u == TT - 1) { hfin0 = v0; hfin1 = v1; }
            }
        } else if (wv < 4) {
            // A burst: A[ub..ub+15] = Wih1 . h0[..], ub = s-17
            if (s >= 17 && s <= 1009 && ((s - 17) & 15) == 0) {
                const int m0 = (wv == 2) ? 0 : 64;
                const int ub = s - 17;
                const int un = ub + (lane & 15);
                h16x8 bf[4];
                #pragma unroll
                for (int kt = 0; kt < 4; ++kt)
                    bf[kt] = *(const h16x8*)(&ring0[un & 31]
                                             [kt * 32 + (lane >> 4) * 8]);
                #pragma unroll
                for (int mt = 0; mt < 4; ++mt) {
                    f32x4 acc = {0.f, 0.f, 0.f, 0.f};
                    #pragma unroll
                    for (int kt = 0; kt < 4; ++kt)
                        acc = __builtin_amdgcn_mfma_f32_16x16x32_f16(
                            W.af[mt][kt], bf[kt], acc, 0, 0, 0);
                    if (un < TT)
                        *(f32x4*)(&A_f[un & 31]
                                  [m0 + mt * 16 + (lane >> 4) * 4]) = acc;
                }
            }
        } else if (wv == 4) {
            // y burst: t = (s-41)+slot; h1[t] written at t+24 <= s-2
            if (s >= 41 && s <= 825 && ((s - 41) & 15) == 0) {
                const int slot = lane >> 2;
                const int c4   = lane & 3;
                const int t    = (s - 41) + slot;
                const _Float16* rb = &ring1[t & 31][0] + c4 * 32;
                float z = 0.f;
                #pragma unroll
                for (int u2 = 0; u2 < 4; ++u2) {
                    h16x8 hv = *(const h16x8*)(rb + 8 * u2);
                    h16x2 hp0 = { hv[0], hv[1] };
                    h16x2 hp1 = { hv[2], hv[3] };
                    h16x2 hp2 = { hv[4], hv[5] };
                    h16x2 hp3 = { hv[6], hv[7] };
                    z = __builtin_amdgcn_fdot2(wo[4 * u2 + 0], hp0, z, false);
                    z = __builtin_amdgcn_fdot2(wo[4 * u2 + 1], hp1, z, false);
                    z = __builtin_amdgcn_fdot2(wo[4 * u2 + 2], hp2, z, false);
                    z = __builtin_amdgcn_fdot2(wo[4 * u2 + 3], hp3, z, false);
                }
                z += dpp_mov<0xB1>(z);
                z += dpp_mov<0x4E>(z);
                if (c4 == 0) y_lds[t] = 1.f / (1.f + expf(-(z + bout)));
            }
        } else {
            // xc burst: t = s+7..s+22 at s = 9+16k
            if (s >= 9 && s <= 777 && ((s - 9) & 15) == 0) {
                xc_burst(s + 7);
            }
        }
        if ((s & 7) == 7) __syncthreads();
    }

    // ---- epilogue: single global dump (last barrier at s=1023) ----
    for (int i = tid; i < TIN; i += 384)
        out[bb * TIN + i] = y_lds[i];
    if (wv == 0)
        *(float2*)(&out[TIN * BATCH + bb * HD + 2 * lane]) = make_float2(hfin0, hfin1);
    else if (wv == 1)
        *(float2*)(&out[TIN * BATCH + BATCH * HD + bb * HD + 2 * lane]) = make_float2(hfin0, hfin1);
}

extern "C" void kernel_launch(void* const* d_in, const int* in_sizes, int n_in,
                              void* d_out, int out_size, void* d_ws, size_t ws_size,
                              hipStream_t stream) {
    (void)in_sizes; (void)n_in; (void)d_ws; (void)ws_size; (void)out_size;
    rnn_rr<<<dim3(BATCH), dim3(384), 0, stream>>>(
        (const float*)d_in[0],  (const float*)d_in[1],
        (const float*)d_in[2],  (const float*)d_in[3],
        (const float*)d_in[4],  (const float*)d_in[5],
        (const float*)d_in[6],  (const float*)d_in[7],
        (const float*)d_in[8],  (const float*)d_in[9],
        (const float*)d_in[10], (const float*)d_in[11],
        (float*)d_out);
}

// Round 11
// 403.468 us; speedup vs baseline: 1.5017x; 1.5017x over previous
//
#include <hip/hip_runtime.h>
#include <math.h>

// 2-layer ReLU RNN, B=256, T=1000 (input 800 + zero pad), H=128, F=5.
// R26 = R23 (champion, 377us rocprof / 885 cyc/step) + micro trims only:
//  (a) step loop unrolled x4: bursts (A@s=17+16k, y@37+16k, xc@9+16k) are
//      all phase 1 mod 4 -> slots 0,2,3 compile-time burst-free; slot 1
//      keeps the runtime mod-16 range checks. 1020 = 4*255 exact.
//  (b) s_setprio(1) around engine matvecs (T5: engines vs bursts share
//      SIMD0/1 -> role diversity exists).
//  (c) xc/A scalar LDS reads issued BEFORE the matvec (latency hidden).
// Ladder verdict (R15-R25): pair-engines + per-step barrier is a stable
// local optimum at 885 cyc/step. Departures all worse: self-contained waves
// (R21 +23%), MFMA recurrence (R22 +44%), pk_fma (R24 +13%), register-ring
// DPP walk (R25 +49%, spill + serial chain). Nulls: wave count 8->6, x-dot
// off critical wave. Residual ~420cyc/step = barrier + post-barrier LDS
// read latency, insensitive to all of the above.
// Structure (384 thr, 6 waves, SIMD=wv&3): wv0,1=h0 engine pair (rows
// 0-63/64-127); wv2,3=h1 engine pair (SK1=20); wv4=A-MFMA half + y burst;
// wv5=A-MFMA half + xc burst. 32-deep LDS rings, windows audited (R19/R20).

#define TT    1000
#define TIN   800
#define HD    128
#define NF    5
#define BATCH 256
#define RS    136           // h16 ring row stride (272B = 17x16B)
#define AS    132           // f32 ring row stride (528B = 33x16B)
#define SK1   20            // h1[u] computed at step u+20
#define NSTEP (TT + SK1)    // 1020 steps = 4*255

typedef _Float16 h16x2 __attribute__((ext_vector_type(2)));
typedef _Float16 h16x8 __attribute__((ext_vector_type(8)));
typedef float    f32x4 __attribute__((ext_vector_type(4)));

template<int CTRL>
__device__ __forceinline__ float dpp_mov(float v) {
    union { float f; int i; } u, r;
    u.f = v;
    r.i = __builtin_amdgcn_update_dpp(0, u.i, CTRL, 0xF, 0xF, true);
    return r.f;
}

__global__ __launch_bounds__(384, 1) void rnn_u4(
    const float* __restrict__ x,        // [256,800,5]
    const float* __restrict__ h_state,  // [2,256,128]
    const float* __restrict__ w_ih0,    // [128,5]
    const float* __restrict__ w_hh0,    // [128,128]
    const float* __restrict__ b_ih0,    // [128]
    const float* __restrict__ b_hh0,    // [128]
    const float* __restrict__ w_ih1,    // [128,128]
    const float* __restrict__ w_hh1,    // [128,128]
    const float* __restrict__ b_ih1,    // [128]
    const float* __restrict__ b_hh1,    // [128]
    const float* __restrict__ w_out,    // [1,128]
    const float* __restrict__ b_out,    // [1]
    float* __restrict__ out)            // [204800 y] ++ [65536 final states]
{
    __shared__ __align__(16) _Float16 x_h[TIN * 8];      // 12.8 KB
    __shared__ __align__(16) _Float16 ring0[32][RS];     // h0 history
    __shared__ __align__(16) _Float16 ring1[32][RS];     // h1 history
    __shared__ __align__(16) float    A_f[32][AS];       // Wih1.h0 ring
    __shared__ __align__(16) float    xc_f[32][AS];      // Wih0.x ring (f32)
    __shared__ float y_lds[TIN];

    const int tid  = threadIdx.x;
    const int bb   = blockIdx.x;
    const int wv   = tid >> 6;          // wave id 0..5 (SIMD = wv&3)
    const int lane = tid & 63;

    // ---- stage x[bb] into LDS (fp16, stride 8, pads zero) ----
    for (int i = tid; i < TIN * 8; i += 384) x_h[i] = (_Float16)0.f;
    __syncthreads();
    for (int i = tid; i < TIN * NF; i += 384) {
        int t = i / 5, f = i - 5 * t;
        x_h[t * 8 + f] = (_Float16)x[bb * (TIN * NF) + i];
    }
    if (tid < HD) {
        ring0[31][tid] = (_Float16)h_state[bb * HD + tid];              // h0[-1]
        ring1[31][tid] = (_Float16)h_state[BATCH * HD + bb * HD + tid]; // h1[-1]
    }

    // ---- h-engine lane geometry (wv 0..3) ----
    const int c    = lane & 3;                      // col chunk (32 cols)
    const int rg   = lane >> 2;                     // row group (4 rows)
    const int g    = 2 * (c & 1) + ((c >> 1) & 1);  // XOR row map (2-bit)
    const int half = wv & 1;
    const int row  = half * 64 + rg * 4 + g;        // lane's final row

    // ---- weight store: 64-VGPR block shared across wave roles ----
    union WU {
        h16x2 wp[4][16];    // wv0-3: rows half*64+rg*4+(j^g), cols c*32..+31
        h16x8 af[4][4];     // wv4,5: Wih1 MFMA A-frags (64-row half)
    } W;
    h16x2 wo[16];           // wv4: wout cols (lane&3)*32..+31
    h16x2 xwa[3], xwb[3];   // wv5: Wih0 rows 2*lane, 2*lane+1
    float bias = 0.f;

    if (wv < 4) {
        const float* Wsrc = (wv < 2) ? w_hh0 : w_hh1;
        #pragma unroll
        for (int j = 0; j < 4; ++j) {
            const float* rp = Wsrc + (half * 64 + rg * 4 + (j ^ g)) * HD + c * 32;
            #pragma unroll
            for (int t = 0; t < 16; ++t) {
                h16x2 w2 = { (_Float16)rp[2 * t], (_Float16)rp[2 * t + 1] };
                W.wp[j][t] = w2;
            }
        }
        bias = (wv < 2) ? (b_ih0[row] + b_hh0[row])
                        : (b_ih1[row] + b_hh1[row]);
    } else {
        // A-frag (16x16x32): lane holds A[m = m0 + mt*16 + (lane&15)]
        //                                [k = kt*32 + (lane>>4)*8 + j]
        const int m0 = (wv == 4) ? 0 : 64;
        #pragma unroll
        for (int mt = 0; mt < 4; ++mt) {
            #pragma unroll
            for (int kt = 0; kt < 4; ++kt) {
                const float* rp = w_ih1 + (m0 + mt * 16 + (lane & 15)) * HD
                                + kt * 32 + (lane >> 4) * 8;
                h16x8 v;
                #pragma unroll
                for (int j = 0; j < 8; ++j) v[j] = (_Float16)rp[j];
                W.af[mt][kt] = v;
            }
        }
        if (wv == 4) {
            const int c4 = lane & 3;
            #pragma unroll
            for (int t = 0; t < 16; ++t) {
                h16x2 w2 = { (_Float16)w_out[c4 * 32 + 2 * t],
                             (_Float16)w_out[c4 * 32 + 2 * t + 1] };
                wo[t] = w2;
            }
        } else {
            #pragma unroll
            for (int k = 0; k < 3; ++k) {
                _Float16 a0 = (_Float16)w_ih0[(2 * lane) * NF + 2 * k];
                _Float16 a1 = (2 * k + 1 < NF) ? (_Float16)w_ih0[(2 * lane) * NF + 2 * k + 1] : (_Float16)0.f;
                _Float16 b0 = (_Float16)w_ih0[(2 * lane + 1) * NF + 2 * k];
                _Float16 b1 = (2 * k + 1 < NF) ? (_Float16)w_ih0[(2 * lane + 1) * NF + 2 * k + 1] : (_Float16)0.f;
                h16x2 wa = { a0, a1 }; xwa[k] = wa;
                h16x2 wb = { b0, b1 }; xwb[k] = wb;
            }
        }
    }
    const float bout = b_out[0];

    float hfin = 0.f;

    __syncthreads();

    // xc burst: lane owns rows 2*lane, 2*lane+1; 16 t's per burst.
    auto xc_burst = [&](int tb) {
        #pragma unroll
        for (int ti = 0; ti < 16; ++ti) {
            const int t = tb + ti;          // uniform across lanes
            h16x8 xv = *(const h16x8*)(&x_h[t * 8]);
            h16x2 xp0 = { xv[0], xv[1] };
            h16x2 xp1 = { xv[2], xv[3] };
            h16x2 xp2 = { xv[4], xv[5] };   // slot 5 is zero pad
            float c0 = __builtin_amdgcn_fdot2(xwa[2], xp2, 0.f, false);
            c0 = __builtin_amdgcn_fdot2(xwa[1], xp1, c0, false);
            c0 = __builtin_amdgcn_fdot2(xwa[0], xp0, c0, false);
            float c1 = __builtin_amdgcn_fdot2(xwb[2], xp2, 0.f, false);
            c1 = __builtin_amdgcn_fdot2(xwb[1], xp1, c1, false);
            c1 = __builtin_amdgcn_fdot2(xwb[0], xp0, c1, false);
            *(float2*)(&xc_f[t & 31][2 * lane]) = make_float2(c0, c1);
        }
    };

    if (wv == 5) xc_burst(0);       // prologue: t = 0..15
    __syncthreads();

    // Tiled matvec (R20-verified): 4 ds_read_b128, 4 rows x 16 fdot2,
    // 2-level DPP tree -> full sum for row rg*4+g.
    auto matvec = [&](const _Float16* base) -> float {
        h16x8 hv[4];
        #pragma unroll
        for (int u2 = 0; u2 < 4; ++u2)
            hv[u2] = *(const h16x8*)(base + c * 32 + 8 * u2);
        float a[4] = {0.f, 0.f, 0.f, 0.f};
        #pragma unroll
        for (int j = 0; j < 4; ++j) {
            float aj = 0.f;
            #pragma unroll
            for (int t = 0; t < 16; ++t) {
                h16x2 hp = { hv[t >> 2][2 * (t & 3)], hv[t >> 2][2 * (t & 3) + 1] };
                aj = __builtin_amdgcn_fdot2(W.wp[j][t], hp, aj, false);
            }
            a[j] = aj;
        }
        a[0] += dpp_mov<0xB1>(a[2]);    // level1 (lane^1, g flips bit1)
        a[1] += dpp_mov<0xB1>(a[3]);
        a[0] += dpp_mov<0x4E>(a[1]);    // level2 (lane^2, g flips bit0)
        return a[0];
    };

    auto step_body = [&](int s, int sp) {
        if (wv < 2) {
            // h0[s] = relu(Whh0.h0[s-1] + xc[s] + b)
            if (s < TT) {
                float xcv = 0.f;
                if (s < TIN) xcv = xc_f[s & 31][row];   // issued pre-matvec
                __builtin_amdgcn_s_setprio(1);
                float v = matvec(&ring0[(s + 31) & 31][0]) + bias + xcv;
                __builtin_amdgcn_s_setprio(0);
                v = fmaxf(v, 0.f);
                ring0[s & 31][row] = (_Float16)v;
                if (s == TT - 1) hfin = v;
            }
        } else if (wv < 4) {
            // h1[u] = relu(Whh1.h1[u-1] + A[u] + b), u = s - 20
            if (s >= SK1) {
                const int u = s - SK1;
                float av = A_f[u & 31][row];            // issued pre-matvec
                __builtin_amdgcn_s_setprio(1);
                float v = matvec(&ring1[(u + 31) & 31][0]);
                __builtin_amdgcn_s_setprio(0);
                v = fmaxf(v + bias + av, 0.f);
                ring1[u & 31][row] = (_Float16)v;
                if (u == TT - 1) hfin = v;
            }
        } else if (sp == 1) {       // all bursts live at s == 1 mod 4
            // A burst (both wv4, wv5): A[ub..ub+15] = Wih1 . h0[..], ub=s-17
            if (s >= 17 && s <= 1009 && ((s - 17) & 15) == 0) {
                const int m0 = (wv == 4) ? 0 : 64;
                const int ub = s - 17;
                const int un = ub + (lane & 15);    // this lane's column step
                h16x8 bf[4];
                #pragma unroll
                for (int kt = 0; kt < 4; ++kt)
                    bf[kt] = *(const h16x8*)(&ring0[un & 31]
                                             [kt * 32 + (lane >> 4) * 8]);
                #pragma unroll
                for (int mt = 0; mt < 4; ++mt) {
                    f32x4 acc = {0.f, 0.f, 0.f, 0.f};
                    #pragma unroll
                    for (int kt = 0; kt < 4; ++kt)
                        acc = __builtin_amdgcn_mfma_f32_16x16x32_f16(
                            W.af[mt][kt], bf[kt], acc, 0, 0, 0);
                    if (un < TT)
                        *(f32x4*)(&A_f[un & 31]
                                  [m0 + mt * 16 + (lane >> 4) * 4]) = acc;
                }
            }
            if (wv == 4) {
                // y burst: t = (s-37)+slot; h1[t] written at t+20 <= s-2
                if (s >= 37 && s <= 821 && ((s - 37) & 15) == 0) {
                    const int slot = lane >> 2;
                    const int c4   = lane & 3;
                    const int t    = (s - 37) + slot;
                    const _Float16* rb = &ring1[t & 31][0] + c4 * 32;
                    float z = 0.f;
                    #pragma unroll
                    for (int u2 = 0; u2 < 4; ++u2) {
                        h16x8 hv = *(const h16x8*)(rb + 8 * u2);
                        h16x2 hp0 = { hv[0], hv[1] };
                        h16x2 hp1 = { hv[2], hv[3] };
                        h16x2 hp2 = { hv[4], hv[5] };
                        h16x2 hp3 = { hv[6], hv[7] };
                        z = __builtin_amdgcn_fdot2(wo[4 * u2 + 0], hp0, z, false);
                        z = __builtin_amdgcn_fdot2(wo[4 * u2 + 1], hp1, z, false);
                        z = __builtin_amdgcn_fdot2(wo[4 * u2 + 2], hp2, z, false);
                        z = __builtin_amdgcn_fdot2(wo[4 * u2 + 3], hp3, z, false);
                    }
                    z += dpp_mov<0xB1>(z);    // xor1 (within quad)
                    z += dpp_mov<0x4E>(z);    // xor2
                    if (c4 == 0) y_lds[t] = 1.f / (1.f + expf(-(z + bout)));
                }
            } else {
                // xc burst: t = 16+16k..31+16k at s = 9+16k (>=7 steps early)
                if (s >= 9 && s <= 777 && ((s - 9) & 15) == 0) {
                    xc_burst(s + 7);
                }
            }
        }
    };

    // unroll x4: bursts all at phase 1 mod 4 -> slots 0,2,3 burst-free
    for (int sb = 0; sb < NSTEP; sb += 4) {
        #pragma unroll
        for (int sp = 0; sp < 4; ++sp) {
            step_body(sb + sp, sp);
            __syncthreads();
        }
    }

    // ---- epilogue: single global dump ----
    for (int i = tid; i < TIN; i += 384)
        out[bb * TIN + i] = y_lds[i];
    if (wv < 2)
        out[TIN * BATCH + bb * HD + row] = hfin;
    else if (wv < 4)
        out[TIN * BATCH + BATCH * HD + bb * HD + row] = hfin;
}

extern "C" void kernel_launch(void* const* d_in, const int* in_sizes, int n_in,
                              void* d_out, int out_size, void* d_ws, size_t ws_size,
                              hipStream_t stream) {
    (void)in_sizes; (void)n_in; (void)d_ws; (void)ws_size; (void)out_size;
    rnn_u4<<<dim3(BATCH), dim3(384), 0, stream>>>(
        (const float*)d_in[0],  (const float*)d_in[1],
        (const float*)d_in[2],  (const float*)d_in[3],
        (const float*)d_in[4],  (const float*)d_in[5],
        (const float*)d_in[6],  (const float*)d_in[7],
        (const float*)d_in[8],  (const float*)d_in[9],
        (const float*)d_in[10], (const float*)d_in[11],
        (float*)d_out);
}